// Round 6
// baseline (167.539 us; speedup 1.0000x reference)
//
#include <hip/hip_runtime.h>
#include <stdint.h>

typedef unsigned long long u64;
typedef unsigned int u32;
typedef u32 v8u __attribute__((ext_vector_type(8)));
typedef u32 v4u __attribute__((ext_vector_type(4)));
typedef int v4i __attribute__((ext_vector_type(4)));

#define K_MSG   1024
#define N_CODE  2048
#define NB      32768
#define KW      16        // 1024 bits / 64 = 16 u64 words per row/col
#define ROWS_TILE 256
#define COLS_TILE 256     // 4 columns per lane

// ---------------- pack b: [NB][K_MSG] int32 -> [NB][KW] u64 ----------------
__global__ void pack_b_kernel(const int* __restrict__ b, u64* __restrict__ bp,
                              int nwords) {
    const int lane  = threadIdx.x & 63;
    const int wave  = blockIdx.x * (blockDim.x >> 6) + (threadIdx.x >> 6);
    const int nwave = gridDim.x * (blockDim.x >> 6);
    for (int word = wave; word < nwords; word += nwave) {
        int v = b[(size_t)word * 64 + lane];
        u64 m = __ballot((v & 1) != 0);
        if (lane == 0) bp[word] = m;
    }
}

// ---------------- pack G: Gp[w][j], bit t = G[w*64+t][j] --------------------
__global__ void pack_g_kernel(const int* __restrict__ G, u64* __restrict__ gp) {
    const int lane = threadIdx.x & 63;
    const int wave = blockIdx.x * (blockDim.x >> 6) + (threadIdx.x >> 6); // 0..511
    const int w    = wave >> 5;   // 0..15
    const int jb   = wave & 31;   // 0..31
    const int j    = jb * 64 + lane;
    u64 word = 0;
#pragma unroll 16
    for (int t = 0; t < 64; ++t) {
        int v = G[(size_t)(w * 64 + t) * N_CODE + j];
        word |= (u64)(v & 1) << t;
    }
    gp[(size_t)w * N_CODE + j] = word;
}

// ---------------- main ------------------------------------------------------
// Block 256 thr = 4 waves; lane owns 4 adjacent columns (256 cols/block), wave
// ty does rows r0+ty, +4, ... (64 iters). Rows in SGPRs via s_load_dwordx8
// ping-pong; ~400 SIMD-cyc of compute per row hides the scalar-load latency.
// Stores: 16B/lane dwordx4, fully coalesced (4KB per wave-instr).

struct RowRegs { v8u a, b, c, d; };   // 32 SGPRs = one 128B packed row

#define SLOAD_ROW(dst, addr)                                            \
    asm volatile("s_load_dwordx8 %0, %4, 0x0\n\t"                       \
                 "s_load_dwordx8 %1, %4, 0x20\n\t"                      \
                 "s_load_dwordx8 %2, %4, 0x40\n\t"                      \
                 "s_load_dwordx8 %3, %4, 0x60"                          \
                 : "=&s"(dst.a), "=&s"(dst.b), "=&s"(dst.c), "=&s"(dst.d) \
                 : "s"(addr))

// rule #18: sched_barrier(0) right after the inline-asm wait so register-only
// consumers of the loaded SGPRs can't be hoisted above it.
#define SWAIT() do { asm volatile("s_waitcnt lgkmcnt(0)" ::: "memory");  \
                     __builtin_amdgcn_sched_barrier(0); } while (0)

#define COMPUTE_STORE(cur, s_) do {                                     \
    v4i r;                                                              \
    _Pragma("unroll")                                                   \
    for (int c = 0; c < 4; ++c) {                                       \
        u32 x0 = 0, x1 = 0, x2 = 0, x3 = 0;                             \
        _Pragma("unroll")                                               \
        for (int i = 0; i < 8; ++i) {                                   \
            x0 ^= cur.a[i] & g[c][i];                                   \
            x1 ^= cur.b[i] & g[c][8 + i];                                \
            x2 ^= cur.c[i] & g[c][16 + i];                               \
            x3 ^= cur.d[i] & g[c][24 + i];                               \
        }                                                               \
        u32 acc = (x0 ^ x1) ^ (x2 ^ x3);                                \
        r[c] = (int)(__popc(acc) & 1);                                  \
    }                                                                   \
    *(v4i*)(op + (size_t)(s_) * 4 * N_CODE) = r;                        \
} while (0)

__global__ __launch_bounds__(256, 3) void encode_main(const u64* __restrict__ bp,
                                                      const u64* __restrict__ gp,
                                                      int* __restrict__ out) {
    const int lane = threadIdx.x & 63;
    const int ty   = threadIdx.x >> 6;
    const int j0   = blockIdx.x * COLS_TILE + lane * 4;
    const int r0   = blockIdx.y * ROWS_TILE;

    // 4 adjacent columns' packed words: 32B contiguous per w -> 2x dwordx4
    u32 g[4][32];
#pragma unroll
    for (int w = 0; w < KW; ++w) {
        v4u q0 = *(const v4u*)(gp + (size_t)w * N_CODE + j0);
        v4u q1 = *(const v4u*)(gp + (size_t)w * N_CODE + j0 + 2);
        g[0][2 * w] = q0.x; g[0][2 * w + 1] = q0.y;
        g[1][2 * w] = q0.z; g[1][2 * w + 1] = q0.w;
        g[2][2 * w] = q1.x; g[2][2 * w + 1] = q1.y;
        g[3][2 * w] = q1.z; g[3][2 * w + 1] = q1.w;
    }

    const int row_u = __builtin_amdgcn_readfirstlane(r0 + ty);
    const u64* rp = bp + ((size_t)row_u << 4);     // +64 u64 per iteration (4 rows)
    int* __restrict__ op = out + (size_t)(r0 + ty) * N_CODE + j0;

    RowRegs A, B;
    SLOAD_ROW(A, rp);
    SWAIT();

#pragma unroll 1
    for (int s = 0; s < 62; s += 2) {
        SLOAD_ROW(B, rp + (size_t)(s + 1) * 64);   // prefetch row s+1
        COMPUTE_STORE(A, s);                       // ~400 cyc hides the latency
        SWAIT();
        SLOAD_ROW(A, rp + (size_t)(s + 2) * 64);   // prefetch row s+2
        COMPUTE_STORE(B, s + 1);
        SWAIT();
    }
    SLOAD_ROW(B, rp + (size_t)63 * 64);
    COMPUTE_STORE(A, 62);
    SWAIT();
    COMPUTE_STORE(B, 63);
}

// ---------------- fallback (only if ws too small) ---------------------------
__global__ void encode_naive(const int* __restrict__ b, const int* __restrict__ G,
                             int* __restrict__ out) {
    size_t idx = (size_t)blockIdx.x * blockDim.x + threadIdx.x;
    size_t total = (size_t)NB * N_CODE;
    if (idx >= total) return;
    int i = (int)(idx / N_CODE);
    int j = (int)(idx % N_CODE);
    int acc = 0;
    for (int k = 0; k < K_MSG; ++k)
        acc ^= b[(size_t)i * K_MSG + k] & G[(size_t)k * N_CODE + j];
    out[idx] = acc & 1;
}

extern "C" void kernel_launch(void* const* d_in, const int* in_sizes, int n_in,
                              void* d_out, int out_size, void* d_ws, size_t ws_size,
                              hipStream_t stream) {
    const int* b = (const int*)d_in[0];
    const int* G = (const int*)d_in[1];
    int* out = (int*)d_out;

    const size_t bp_bytes = (size_t)NB * KW * sizeof(u64);      // 4 MiB
    const size_t gp_bytes = (size_t)N_CODE * KW * sizeof(u64);  // 256 KiB

    if (ws_size < bp_bytes + gp_bytes) {
        size_t total = (size_t)NB * N_CODE;
        encode_naive<<<(unsigned)((total + 255) / 256), 256, 0, stream>>>(b, G, out);
        return;
    }

    u64* bp = (u64*)d_ws;
    u64* gp = (u64*)((char*)d_ws + bp_bytes);

    pack_b_kernel<<<2048, 256, 0, stream>>>(b, bp, NB * KW);
    pack_g_kernel<<<128, 256, 0, stream>>>(G, gp);

    dim3 grid(N_CODE / COLS_TILE, NB / ROWS_TILE);  // 8 x 128 = 1024 blocks
    encode_main<<<grid, 256, 0, stream>>>(bp, gp, out);
}

// Round 7
// 160.947 us; speedup vs baseline: 1.0410x; 1.0410x over previous
//
#include <hip/hip_runtime.h>
#include <stdint.h>

typedef unsigned long long u64;
typedef unsigned int u32;
typedef u32 v4u __attribute__((ext_vector_type(4)));
typedef int v4i __attribute__((ext_vector_type(4)));

#define K_MSG   1024
#define N_CODE  2048
#define NB      32768
#define KW      16          // 16 u64 words per row/col (1024 bits)
#define ROWS_TILE 128       // rows staged per block: 128 * 128B = 16 KB LDS
#define COLS_TILE 1024      // 256 thr * 4 cols

// Bit-order convention (must match between pack_b and pack_g; encode is
// order-agnostic): word w = g*4+s (g=0..3 group of 256 k's, s=0..3), bit p of
// word w <-> k = g*256 + 4*p + s.

// ---------------- pack b: [NB][K_MSG] int32 -> [NB][KW] u64 ----------------
// One wave-iter per (row,group) pair: lane l loads int4 at k = g*256+4l (16B/lane,
// fully coalesced 1KB/wave); 4 ballots give the 4 words of the group.
__global__ void pack_b_kernel(const int* __restrict__ b, u64* __restrict__ bp) {
    const int lane  = threadIdx.x & 63;
    const int wave  = blockIdx.x * (blockDim.x >> 6) + (threadIdx.x >> 6);
    const int nwave = gridDim.x * (blockDim.x >> 6);
    const int niter = NB * 4;                       // (row,group) pairs
    for (int idx = wave; idx < niter; idx += nwave) {
        // idx = row*4 + g  ->  element base = row*1024 + g*256
        int4 v = *(const int4*)(b + (size_t)idx * 256 + lane * 4);
        u64 m0 = __ballot((v.x & 1) != 0);
        u64 m1 = __ballot((v.y & 1) != 0);
        u64 m2 = __ballot((v.z & 1) != 0);
        u64 m3 = __ballot((v.w & 1) != 0);
        if (lane == 0) {
            u64* d = bp + (size_t)idx * 4;
            d[0] = m0; d[1] = m1; d[2] = m2; d[3] = m3;
        }
    }
}

// ---------------- pack G: gp[w*N_CODE+j], bit t = G[g*256+4t+s][j] ----------
__global__ void pack_g_kernel(const int* __restrict__ G, u64* __restrict__ gp) {
    const int lane = threadIdx.x & 63;
    const int wave = blockIdx.x * (blockDim.x >> 6) + (threadIdx.x >> 6); // 0..511
    const int w    = wave >> 5;   // 0..15
    const int jb   = wave & 31;   // 0..31
    const int j    = jb * 64 + lane;
    const int g    = w >> 2;
    const int s    = w & 3;
    u64 word = 0;
#pragma unroll 16
    for (int t = 0; t < 64; ++t) {
        int v = G[(size_t)(g * 256 + 4 * t + s) * N_CODE + j];
        word |= (u64)(v & 1) << t;
    }
    gp[(size_t)w * N_CODE + j] = word;
}

// ---------------- main ------------------------------------------------------
// Block 256 thr = 4 waves; thread owns 4 adjacent columns (1024 cols/block).
// 128-row tile staged in 16 KB LDS; per row: 8x ds_read_b128 broadcast
// (in-order returns, compiler-counted lgkmcnt, ~120cy latency) + 4 AND/XOR
// trees sharing the row words + one coalesced dwordx4 store (1KB/wave).
__global__ __launch_bounds__(256, 2) void encode_main(const u64* __restrict__ bp,
                                                      const u64* __restrict__ gp,
                                                      int* __restrict__ out) {
    __shared__ v4u rows_v[ROWS_TILE * 8];            // 16 KB, 16B-aligned
    u32* rows = (u32*)rows_v;

    const int tid = threadIdx.x;
    const int j0  = blockIdx.x * COLS_TILE + tid * 4;
    const int r0  = blockIdx.y * ROWS_TILE;

    // 4 adjacent columns' packed words: 128 VGPRs, compile-time indexed only
    u32 g[4][32];
#pragma unroll
    for (int w = 0; w < KW; ++w) {
        v4u q0 = *(const v4u*)(gp + (size_t)w * N_CODE + j0);
        v4u q1 = *(const v4u*)(gp + (size_t)w * N_CODE + j0 + 2);
        g[0][2 * w] = q0.x; g[0][2 * w + 1] = q0.y;
        g[1][2 * w] = q0.z; g[1][2 * w + 1] = q0.w;
        g[2][2 * w] = q1.x; g[2][2 * w + 1] = q1.y;
        g[3][2 * w] = q1.z; g[3][2 * w + 1] = q1.w;
    }

    // stage the row tile: contiguous 16 KB of bp starting at row r0
    {
        const v4u* __restrict__ src = (const v4u*)(bp + ((size_t)r0 << 4));
#pragma unroll
        for (int i = 0; i < 4; ++i)
            rows_v[tid + 256 * i] = src[tid + 256 * i];
    }
    __syncthreads();

    int* __restrict__ op = out + (size_t)r0 * N_CODE + j0;

#pragma unroll 2
    for (int r = 0; r < ROWS_TILE; ++r) {
        const u32* rw = &rows[r * 32];
        v4i res;
#pragma unroll
        for (int c = 0; c < 4; ++c) {
            u32 x0 = 0, x1 = 0, x2 = 0, x3 = 0;
#pragma unroll
            for (int i = 0; i < 8; ++i) {
                x0 ^= rw[i]      & g[c][i];
                x1 ^= rw[8 + i]  & g[c][8 + i];
                x2 ^= rw[16 + i] & g[c][16 + i];
                x3 ^= rw[24 + i] & g[c][24 + i];
            }
            u32 acc = (x0 ^ x1) ^ (x2 ^ x3);
            res[c] = (int)(__popc(acc) & 1);
        }
        *(v4i*)(op + (size_t)r * N_CODE) = res;
    }
}

// ---------------- fallback (only if ws too small) ---------------------------
__global__ void encode_naive(const int* __restrict__ b, const int* __restrict__ G,
                             int* __restrict__ out) {
    size_t idx = (size_t)blockIdx.x * blockDim.x + threadIdx.x;
    size_t total = (size_t)NB * N_CODE;
    if (idx >= total) return;
    int i = (int)(idx / N_CODE);
    int j = (int)(idx % N_CODE);
    int acc = 0;
    for (int k = 0; k < K_MSG; ++k)
        acc ^= b[(size_t)i * K_MSG + k] & G[(size_t)k * N_CODE + j];
    out[idx] = acc & 1;
}

extern "C" void kernel_launch(void* const* d_in, const int* in_sizes, int n_in,
                              void* d_out, int out_size, void* d_ws, size_t ws_size,
                              hipStream_t stream) {
    const int* b = (const int*)d_in[0];
    const int* G = (const int*)d_in[1];
    int* out = (int*)d_out;

    const size_t bp_bytes = (size_t)NB * KW * sizeof(u64);      // 4 MiB
    const size_t gp_bytes = (size_t)N_CODE * KW * sizeof(u64);  // 256 KiB

    if (ws_size < bp_bytes + gp_bytes) {
        size_t total = (size_t)NB * N_CODE;
        encode_naive<<<(unsigned)((total + 255) / 256), 256, 0, stream>>>(b, G, out);
        return;
    }

    u64* bp = (u64*)d_ws;
    u64* gp = (u64*)((char*)d_ws + bp_bytes);

    pack_b_kernel<<<2048, 256, 0, stream>>>(b, bp);
    pack_g_kernel<<<128, 256, 0, stream>>>(G, gp);

    dim3 grid(N_CODE / COLS_TILE, NB / ROWS_TILE);  // 2 x 256 = 512 blocks
    encode_main<<<grid, 256, 0, stream>>>(bp, gp, out);
}